// Round 1
// baseline (566.557 us; speedup 1.0000x reference)
//
#include <hip/hip_runtime.h>
#include <cmath>

#define N_NODES 50000
#define N_EDGES 800000
// IN_DIM = HEADS*HID = 128, HEADS=4, HID=32

static __device__ __forceinline__ float lrelu(float x) { return x > 0.f ? x : 0.2f * x; }

// ---------------- CSR build ----------------
__global__ __launch_bounds__(256) void count_k(const int* __restrict__ dst, int* __restrict__ cnt) {
    int e = blockIdx.x * 256 + threadIdx.x;
    if (e < N_EDGES) atomicAdd(&cnt[dst[e]], 1);
}

__global__ __launch_bounds__(1024) void scan_k(const int* __restrict__ cnt, int* __restrict__ offs,
                                               int* __restrict__ fillpos) {
    __shared__ int sums[1024];
    const int n = N_NODES;
    const int CH = (n + 1023) / 1024;  // 49
    int tid = threadIdx.x;
    int beg = tid * CH;
    int end = beg + CH < n ? beg + CH : n;
    int s = 0;
    for (int i = beg; i < end; ++i) s += cnt[i];
    sums[tid] = s;
    __syncthreads();
    for (int off = 1; off < 1024; off <<= 1) {
        int v = (tid >= off) ? sums[tid - off] : 0;
        __syncthreads();
        sums[tid] += v;
        __syncthreads();
    }
    int base = (tid == 0) ? 0 : sums[tid - 1];
    for (int i = beg; i < end; ++i) {
        offs[i] = base;
        fillpos[i] = base;
        base += cnt[i];
    }
    if (tid == 1023) offs[n] = sums[1023];  // total = N_EDGES
}

__global__ __launch_bounds__(256) void fill_k(const int* __restrict__ src, const int* __restrict__ dst,
                                              int* __restrict__ fillpos, int2* __restrict__ pair) {
    int e = blockIdx.x * 256 + threadIdx.x;
    if (e >= N_EDGES) return;
    int d = dst[e];
    int pos = atomicAdd(&fillpos[d], 1);
    pair[pos] = make_int2(e, src[e]);  // (edge id, src node)
}

// ---------------- GEMM (X[N,128] @ W[128,128]) fused with el/er head dots ----------------
// block: 256 threads, 64 rows x 128 cols per block. tx = col4 (0..31), ty = 0..7, rows = ty + 8*i.
__global__ __launch_bounds__(256) void gemm_attn(
    const float* __restrict__ X, const float* __restrict__ W,
    const float* __restrict__ al, const float* __restrict__ ar,
    float* __restrict__ hf, float* __restrict__ el, float* __restrict__ er, int n)
{
    __shared__ float xs[64][128];
    int row0 = blockIdx.x * 64;
    int tid = threadIdx.x;
    const float4* X4 = (const float4*)X;
    for (int i = tid; i < 64 * 32; i += 256) {
        int r = i >> 5, c = i & 31;
        float4 v = make_float4(0.f, 0.f, 0.f, 0.f);
        if (row0 + r < n) v = X4[(size_t)(row0 + r) * 32 + c];
        ((float4*)&xs[r][0])[c] = v;
    }
    __syncthreads();

    int tx = tid & 31;   // col4
    int ty = tid >> 5;   // 0..7
    float4 acc[8];
#pragma unroll
    for (int i = 0; i < 8; i++) acc[i] = make_float4(0.f, 0.f, 0.f, 0.f);

    const float4* W4 = (const float4*)W;
    for (int k4 = 0; k4 < 32; ++k4) {
        float4 w0 = W4[(4 * k4 + 0) * 32 + tx];
        float4 w1 = W4[(4 * k4 + 1) * 32 + tx];
        float4 w2 = W4[(4 * k4 + 2) * 32 + tx];
        float4 w3 = W4[(4 * k4 + 3) * 32 + tx];
#pragma unroll
        for (int i = 0; i < 8; i++) {
            float4 x = ((const float4*)&xs[ty + i * 8][0])[k4];
            acc[i].x += x.x * w0.x + x.y * w1.x + x.z * w2.x + x.w * w3.x;
            acc[i].y += x.x * w0.y + x.y * w1.y + x.z * w2.y + x.w * w3.y;
            acc[i].z += x.x * w0.z + x.y * w1.z + x.z * w2.z + x.w * w3.z;
            acc[i].w += x.x * w0.w + x.y * w1.w + x.z * w2.w + x.w * w3.w;
        }
    }

    // epilogue: store hf, compute el/er per (row, head)
    int head = tx >> 3;   // 4 cols*8 threads = 32 cols per head
    int sub = tx & 7;
    float4 av = ((const float4*)al)[head * 8 + sub];
    float4 rv = ((const float4*)ar)[head * 8 + sub];
#pragma unroll
    for (int i = 0; i < 8; i++) {
        int row = row0 + ty + i * 8;
        float pel = acc[i].x * av.x + acc[i].y * av.y + acc[i].z * av.z + acc[i].w * av.w;
        float per = acc[i].x * rv.x + acc[i].y * rv.y + acc[i].z * rv.z + acc[i].w * rv.w;
        pel += __shfl_xor(pel, 1); pel += __shfl_xor(pel, 2); pel += __shfl_xor(pel, 4);
        per += __shfl_xor(per, 1); per += __shfl_xor(per, 2); per += __shfl_xor(per, 4);
        if (row < n) {
            ((float4*)hf)[(size_t)row * 32 + tx] = acc[i];
            if (sub == 0) {
                el[row * 4 + head] = pel;
                er[row * 4 + head] = per;
            }
        }
    }
}

// ---------------- per-edge softmax numerator w = exp(leaky_relu(el[src]+er[dst])) ----------------
__global__ __launch_bounds__(256) void edge_w_k(const int* __restrict__ src, const int* __restrict__ dst,
                                                const float4* __restrict__ el4, const float4* __restrict__ er4,
                                                float4* __restrict__ w4) {
    int e = blockIdx.x * 256 + threadIdx.x;
    if (e >= N_EDGES) return;
    float4 a = el4[src[e]];
    float4 b = er4[dst[e]];
    float4 r;
    r.x = expf(lrelu(a.x + b.x));
    r.y = expf(lrelu(a.y + b.y));
    r.z = expf(lrelu(a.z + b.z));
    r.w = expf(lrelu(a.w + b.w));
    w4[e] = r;
}

// ---------------- dst-centric aggregation: one wave per node, lane owns 2 floats ----------------
__global__ __launch_bounds__(256) void agg_k(const int* __restrict__ offs, const int2* __restrict__ pair,
                                             const float* __restrict__ w, const float* __restrict__ hf,
                                             const float* __restrict__ bias, float* __restrict__ out,
                                             int do_relu) {
    int node = blockIdx.x * 4 + (threadIdx.x >> 6);
    int lane = threadIdx.x & 63;
    if (node >= N_NODES) return;
    int beg = offs[node];
    int end = offs[node + 1];
    int h = lane >> 4;  // head of the 2 floats this lane owns
    const float2* hf2 = (const float2*)hf;
    float ax = 0.f, ay = 0.f, den = 0.f;
    for (int j = beg; j < end; ++j) {
        int2 p = pair[j];                       // broadcast 8B
        float wv = w[(size_t)p.x * 4 + h];      // broadcast 16B line
        float2 x = hf2[(size_t)p.y * 64 + lane];// coalesced 512B row gather
        ax += wv * x.x;
        ay += wv * x.y;
        den += wv;
    }
    float inv = 1.0f / fmaxf(den, 1e-30f);
    float o0 = ax * inv + bias[lane * 2];
    float o1 = ay * inv + bias[lane * 2 + 1];
    if (do_relu) { o0 = fmaxf(o0, 0.f); o1 = fmaxf(o1, 0.f); }
    ((float2*)out)[(size_t)node * 64 + lane] = make_float2(o0, o1);
}

// ---------------- head-mean -> relu -> [32,2] proj -> softmax ----------------
__global__ __launch_bounds__(256) void final_k(const float* __restrict__ h2, const float* __restrict__ Wout,
                                               const float* __restrict__ bout, float* __restrict__ out) {
    int tid = threadIdx.x;
    int node = blockIdx.x * 8 + (tid >> 5);
    int d = tid & 31;
    if (node >= N_NODES) return;
    const float* row = h2 + (size_t)node * 128;
    float m = 0.25f * (row[d] + row[32 + d] + row[64 + d] + row[96 + d]);
    float r = fmaxf(m, 0.f);
    float l0 = r * Wout[d * 2];
    float l1 = r * Wout[d * 2 + 1];
#pragma unroll
    for (int off = 16; off; off >>= 1) {
        l0 += __shfl_xor(l0, off, 32);
        l1 += __shfl_xor(l1, off, 32);
    }
    if (d == 0) {
        l0 += bout[0];
        l1 += bout[1];
        float mx = fmaxf(l0, l1);
        float e0 = expf(l0 - mx), e1 = expf(l1 - mx);
        float inv = 1.f / (e0 + e1);
        ((float2*)out)[node] = make_float2(e0 * inv, e1 * inv);
    }
}

extern "C" void kernel_launch(void* const* d_in, const int* in_sizes, int n_in,
                              void* d_out, int out_size, void* d_ws, size_t ws_size,
                              hipStream_t stream) {
    const float* in_feat = (const float*)d_in[0];
    const float* W1   = (const float*)d_in[1];
    const float* al1  = (const float*)d_in[2];
    const float* ar1  = (const float*)d_in[3];
    const float* b1   = (const float*)d_in[4];
    const float* W2   = (const float*)d_in[5];
    const float* al2  = (const float*)d_in[6];
    const float* ar2  = (const float*)d_in[7];
    const float* b2   = (const float*)d_in[8];
    const float* Wout = (const float*)d_in[9];
    const float* bout = (const float*)d_in[10];
    const int*   src  = (const int*)d_in[11];
    const int*   dst  = (const int*)d_in[12];
    float* out = (float*)d_out;

    // workspace carve-up (256B aligned)
    char* ws = (char*)d_ws;
    size_t off = 0;
    auto carve = [&](size_t bytes) {
        char* p = ws + off;
        off = (off + bytes + 255) & ~(size_t)255;
        return p;
    };
    float* hfA   = (float*)carve((size_t)N_NODES * 128 * 4);  // hf layer1, then hf layer2
    float* hB    = (float*)carve((size_t)N_NODES * 128 * 4);  // h1 (relu), then h2
    float* el    = (float*)carve((size_t)N_NODES * 4 * 4);
    float* er    = (float*)carve((size_t)N_NODES * 4 * 4);
    float* w4    = (float*)carve((size_t)N_EDGES * 4 * 4);
    int2*  pair  = (int2*)carve((size_t)N_EDGES * 8);
    int*   cnt   = (int*)carve((size_t)N_NODES * 4);
    int*   offs  = (int*)carve((size_t)(N_NODES + 1) * 4);
    int*   fillp = (int*)carve((size_t)N_NODES * 4);
    (void)ws_size; (void)in_sizes; (void)n_in; (void)out_size;

    const int EB = (N_EDGES + 255) / 256;        // 3125
    const int GB = (N_NODES + 63) / 64;          // 782
    const int AB = (N_NODES + 3) / 4;            // 12500
    const int FB = (N_NODES + 7) / 8;            // 6250

    // CSR build (shared by both layers)
    hipMemsetAsync(cnt, 0, (size_t)N_NODES * 4, stream);
    count_k<<<EB, 256, 0, stream>>>(dst, cnt);
    scan_k<<<1, 1024, 0, stream>>>(cnt, offs, fillp);
    fill_k<<<EB, 256, 0, stream>>>(src, dst, fillp, pair);

    // layer 1
    gemm_attn<<<GB, 256, 0, stream>>>(in_feat, W1, al1, ar1, hfA, el, er, N_NODES);
    edge_w_k<<<EB, 256, 0, stream>>>(src, dst, (const float4*)el, (const float4*)er, (float4*)w4);
    agg_k<<<AB, 256, 0, stream>>>(offs, pair, w4, hfA, b1, hB, 1);

    // layer 2
    gemm_attn<<<GB, 256, 0, stream>>>(hB, W2, al2, ar2, hfA, el, er, N_NODES);
    edge_w_k<<<EB, 256, 0, stream>>>(src, dst, (const float4*)el, (const float4*)er, (float4*)w4);
    agg_k<<<AB, 256, 0, stream>>>(offs, pair, w4, hfA, b2, hB, 0);

    // head
    final_k<<<FB, 256, 0, stream>>>(hB, Wout, bout, out);
}

// Round 2
// 426.876 us; speedup vs baseline: 1.3272x; 1.3272x over previous
//
#include <hip/hip_runtime.h>
#include <cmath>

#define N_NODES 50000
#define N_EDGES 800000
#define NB_SCAN ((N_NODES + 255) / 256)   // 196
// IN_DIM = HEADS*HID = 128, HEADS=4, HID=32

static __device__ __forceinline__ float lrelu(float x) { return x > 0.f ? x : 0.2f * x; }

// ---------------- CSR build ----------------
__global__ __launch_bounds__(256) void count_k(const int* __restrict__ dst, int* __restrict__ cnt) {
    int e = blockIdx.x * 256 + threadIdx.x;
    if (e < N_EDGES) atomicAdd(&cnt[dst[e]], 1);
}

// stage 1: per-block (256 elems) sums
__global__ __launch_bounds__(256) void partial_k(const int* __restrict__ cnt, int* __restrict__ bsum) {
    int i = blockIdx.x * 256 + threadIdx.x;
    int v = (i < N_NODES) ? cnt[i] : 0;
#pragma unroll
    for (int o = 1; o < 64; o <<= 1) v += __shfl_xor(v, o);
    __shared__ int s[4];
    if ((threadIdx.x & 63) == 0) s[threadIdx.x >> 6] = v;
    __syncthreads();
    if (threadIdx.x == 0) bsum[blockIdx.x] = s[0] + s[1] + s[2] + s[3];
}

// stage 2: single-block exclusive scan of the 196 block sums
__global__ __launch_bounds__(256) void scanb_k(int* __restrict__ bsum) {
    __shared__ int s[256];
    int tid = threadIdx.x;
    int v = (tid < NB_SCAN) ? bsum[tid] : 0;
    s[tid] = v;
    __syncthreads();
    for (int o = 1; o < 256; o <<= 1) {
        int t = (tid >= o) ? s[tid - o] : 0;
        __syncthreads();
        s[tid] += t;
        __syncthreads();
    }
    if (tid < NB_SCAN) bsum[tid] = (tid == 0) ? 0 : s[tid - 1];
}

// stage 3: per-element exclusive scan = blockOffset + waveOffset + waveScan
__global__ __launch_bounds__(256) void expand_k(const int* __restrict__ cnt, const int* __restrict__ bsum,
                                                int* __restrict__ offs, int* __restrict__ fillpos) {
    int i = blockIdx.x * 256 + threadIdx.x;
    int lane = threadIdx.x & 63, wid = threadIdx.x >> 6;
    int v = (i < N_NODES) ? cnt[i] : 0;
    int orig = v;
#pragma unroll
    for (int o = 1; o < 64; o <<= 1) {
        int t = __shfl_up(v, o);
        if (lane >= o) v += t;
    }
    __shared__ int ws[4];
    if (lane == 63) ws[wid] = v;
    __syncthreads();
    int woff = 0;
#pragma unroll
    for (int k = 0; k < 4; k++)
        if (k < wid) woff += ws[k];
    int ex = bsum[blockIdx.x] + woff + (v - orig);
    if (i < N_NODES) {
        offs[i] = ex;
        fillpos[i] = ex;
    }
    if (i == N_NODES - 1) offs[N_NODES] = ex + orig;
}

__global__ __launch_bounds__(256) void fill_k(const int* __restrict__ src, const int* __restrict__ dst,
                                              int* __restrict__ fillpos, int2* __restrict__ pair) {
    int e = blockIdx.x * 256 + threadIdx.x;
    if (e >= N_EDGES) return;
    int d = dst[e];
    int pos = atomicAdd(&fillpos[d], 1);
    pair[pos] = make_int2(e, src[e]);  // (edge id, src node)
}

// ---------------- GEMM (X[N,128] @ W[128,128]) fused with el/er head dots ----------------
__global__ __launch_bounds__(256) void gemm_attn(
    const float* __restrict__ X, const float* __restrict__ W,
    const float* __restrict__ al, const float* __restrict__ ar,
    float* __restrict__ hf, float* __restrict__ el, float* __restrict__ er, int n)
{
    __shared__ float xs[64][128];
    int row0 = blockIdx.x * 64;
    int tid = threadIdx.x;
    const float4* X4 = (const float4*)X;
    for (int i = tid; i < 64 * 32; i += 256) {
        int r = i >> 5, c = i & 31;
        float4 v = make_float4(0.f, 0.f, 0.f, 0.f);
        if (row0 + r < n) v = X4[(size_t)(row0 + r) * 32 + c];
        ((float4*)&xs[r][0])[c] = v;
    }
    __syncthreads();

    int tx = tid & 31;   // col4
    int ty = tid >> 5;   // 0..7
    float4 acc[8];
#pragma unroll
    for (int i = 0; i < 8; i++) acc[i] = make_float4(0.f, 0.f, 0.f, 0.f);

    const float4* W4 = (const float4*)W;
    for (int k4 = 0; k4 < 32; ++k4) {
        float4 w0 = W4[(4 * k4 + 0) * 32 + tx];
        float4 w1 = W4[(4 * k4 + 1) * 32 + tx];
        float4 w2 = W4[(4 * k4 + 2) * 32 + tx];
        float4 w3 = W4[(4 * k4 + 3) * 32 + tx];
#pragma unroll
        for (int i = 0; i < 8; i++) {
            float4 x = ((const float4*)&xs[ty + i * 8][0])[k4];
            acc[i].x += x.x * w0.x + x.y * w1.x + x.z * w2.x + x.w * w3.x;
            acc[i].y += x.x * w0.y + x.y * w1.y + x.z * w2.y + x.w * w3.y;
            acc[i].z += x.x * w0.z + x.y * w1.z + x.z * w2.z + x.w * w3.z;
            acc[i].w += x.x * w0.w + x.y * w1.w + x.z * w2.w + x.w * w3.w;
        }
    }

    int head = tx >> 3;
    int sub = tx & 7;
    float4 av = ((const float4*)al)[head * 8 + sub];
    float4 rv = ((const float4*)ar)[head * 8 + sub];
#pragma unroll
    for (int i = 0; i < 8; i++) {
        int row = row0 + ty + i * 8;
        float pel = acc[i].x * av.x + acc[i].y * av.y + acc[i].z * av.z + acc[i].w * av.w;
        float per = acc[i].x * rv.x + acc[i].y * rv.y + acc[i].z * rv.z + acc[i].w * rv.w;
        pel += __shfl_xor(pel, 1); pel += __shfl_xor(pel, 2); pel += __shfl_xor(pel, 4);
        per += __shfl_xor(per, 1); per += __shfl_xor(per, 2); per += __shfl_xor(per, 4);
        if (row < n) {
            ((float4*)hf)[(size_t)row * 32 + tx] = acc[i];
            if (sub == 0) {
                el[row * 4 + head] = pel;
                er[row * 4 + head] = per;
            }
        }
    }
}

// ---------------- per-edge softmax numerator ----------------
__global__ __launch_bounds__(256) void edge_w_k(const int* __restrict__ src, const int* __restrict__ dst,
                                                const float4* __restrict__ el4, const float4* __restrict__ er4,
                                                float4* __restrict__ w4) {
    int e = blockIdx.x * 256 + threadIdx.x;
    if (e >= N_EDGES) return;
    float4 a = el4[src[e]];
    float4 b = er4[dst[e]];
    float4 r;
    r.x = expf(lrelu(a.x + b.x));
    r.y = expf(lrelu(a.y + b.y));
    r.z = expf(lrelu(a.z + b.z));
    r.w = expf(lrelu(a.w + b.w));
    w4[e] = r;
}

// ---------------- dst-centric aggregation: one wave per node, lane owns 2 floats ----------------
__global__ __launch_bounds__(256) void agg_k(const int* __restrict__ offs, const int2* __restrict__ pair,
                                             const float* __restrict__ w, const float* __restrict__ hf,
                                             const float* __restrict__ bias, float* __restrict__ out,
                                             int do_relu) {
    int node = blockIdx.x * 4 + (threadIdx.x >> 6);
    int lane = threadIdx.x & 63;
    if (node >= N_NODES) return;
    int beg = offs[node];
    int end = offs[node + 1];
    int h = lane >> 4;
    const float2* hf2 = (const float2*)hf;
    float ax = 0.f, ay = 0.f, den = 0.f;
    int j = beg;
    // unroll-by-2: two independent pair->w/hf gather chains in flight
    for (; j + 1 < end; j += 2) {
        int2 p0 = pair[j];
        int2 p1 = pair[j + 1];
        float w0 = w[(size_t)p0.x * 4 + h];
        float w1 = w[(size_t)p1.x * 4 + h];
        float2 x0 = hf2[(size_t)p0.y * 64 + lane];
        float2 x1 = hf2[(size_t)p1.y * 64 + lane];
        ax += w0 * x0.x + w1 * x1.x;
        ay += w0 * x0.y + w1 * x1.y;
        den += w0 + w1;
    }
    if (j < end) {
        int2 p = pair[j];
        float wv = w[(size_t)p.x * 4 + h];
        float2 x = hf2[(size_t)p.y * 64 + lane];
        ax += wv * x.x;
        ay += wv * x.y;
        den += wv;
    }
    float inv = 1.0f / fmaxf(den, 1e-30f);
    float o0 = ax * inv + bias[lane * 2];
    float o1 = ay * inv + bias[lane * 2 + 1];
    if (do_relu) { o0 = fmaxf(o0, 0.f); o1 = fmaxf(o1, 0.f); }
    ((float2*)out)[(size_t)node * 64 + lane] = make_float2(o0, o1);
}

// ---------------- head-mean -> relu -> [32,2] proj -> softmax ----------------
__global__ __launch_bounds__(256) void final_k(const float* __restrict__ h2, const float* __restrict__ Wout,
                                               const float* __restrict__ bout, float* __restrict__ out) {
    int tid = threadIdx.x;
    int node = blockIdx.x * 8 + (tid >> 5);
    int d = tid & 31;
    if (node >= N_NODES) return;
    const float* row = h2 + (size_t)node * 128;
    float m = 0.25f * (row[d] + row[32 + d] + row[64 + d] + row[96 + d]);
    float r = fmaxf(m, 0.f);
    float l0 = r * Wout[d * 2];
    float l1 = r * Wout[d * 2 + 1];
#pragma unroll
    for (int off = 16; off; off >>= 1) {
        l0 += __shfl_xor(l0, off, 32);
        l1 += __shfl_xor(l1, off, 32);
    }
    if (d == 0) {
        l0 += bout[0];
        l1 += bout[1];
        float mx = fmaxf(l0, l1);
        float e0 = expf(l0 - mx), e1 = expf(l1 - mx);
        float inv = 1.f / (e0 + e1);
        ((float2*)out)[node] = make_float2(e0 * inv, e1 * inv);
    }
}

extern "C" void kernel_launch(void* const* d_in, const int* in_sizes, int n_in,
                              void* d_out, int out_size, void* d_ws, size_t ws_size,
                              hipStream_t stream) {
    const float* in_feat = (const float*)d_in[0];
    const float* W1   = (const float*)d_in[1];
    const float* al1  = (const float*)d_in[2];
    const float* ar1  = (const float*)d_in[3];
    const float* b1   = (const float*)d_in[4];
    const float* W2   = (const float*)d_in[5];
    const float* al2  = (const float*)d_in[6];
    const float* ar2  = (const float*)d_in[7];
    const float* b2   = (const float*)d_in[8];
    const float* Wout = (const float*)d_in[9];
    const float* bout = (const float*)d_in[10];
    const int*   src  = (const int*)d_in[11];
    const int*   dst  = (const int*)d_in[12];
    float* out = (float*)d_out;

    char* ws = (char*)d_ws;
    size_t off = 0;
    auto carve = [&](size_t bytes) {
        char* p = ws + off;
        off = (off + bytes + 255) & ~(size_t)255;
        return p;
    };
    float* hfA   = (float*)carve((size_t)N_NODES * 128 * 4);
    float* hB    = (float*)carve((size_t)N_NODES * 128 * 4);
    float* el    = (float*)carve((size_t)N_NODES * 4 * 4);
    float* er    = (float*)carve((size_t)N_NODES * 4 * 4);
    float* w4    = (float*)carve((size_t)N_EDGES * 4 * 4);
    int2*  pair  = (int2*)carve((size_t)N_EDGES * 8);
    int*   cnt   = (int*)carve((size_t)N_NODES * 4);
    int*   offs  = (int*)carve((size_t)(N_NODES + 1) * 4);
    int*   fillp = (int*)carve((size_t)N_NODES * 4);
    int*   bsum  = (int*)carve((size_t)NB_SCAN * 4);
    (void)ws_size; (void)in_sizes; (void)n_in; (void)out_size;

    const int EB = (N_EDGES + 255) / 256;        // 3125
    const int GB = (N_NODES + 63) / 64;          // 782
    const int AB = (N_NODES + 3) / 4;            // 12500
    const int FB = (N_NODES + 7) / 8;            // 6250

    // CSR build (shared by both layers)
    hipMemsetAsync(cnt, 0, (size_t)N_NODES * 4, stream);
    count_k<<<EB, 256, 0, stream>>>(dst, cnt);
    partial_k<<<NB_SCAN, 256, 0, stream>>>(cnt, bsum);
    scanb_k<<<1, 256, 0, stream>>>(bsum);
    expand_k<<<NB_SCAN, 256, 0, stream>>>(cnt, bsum, offs, fillp);
    fill_k<<<EB, 256, 0, stream>>>(src, dst, fillp, pair);

    // layer 1
    gemm_attn<<<GB, 256, 0, stream>>>(in_feat, W1, al1, ar1, hfA, el, er, N_NODES);
    edge_w_k<<<EB, 256, 0, stream>>>(src, dst, (const float4*)el, (const float4*)er, (float4*)w4);
    agg_k<<<AB, 256, 0, stream>>>(offs, pair, w4, hfA, b1, hB, 1);

    // layer 2
    gemm_attn<<<GB, 256, 0, stream>>>(hB, W2, al2, ar2, hfA, el, er, N_NODES);
    edge_w_k<<<EB, 256, 0, stream>>>(src, dst, (const float4*)el, (const float4*)er, (float4*)w4);
    agg_k<<<AB, 256, 0, stream>>>(offs, pair, w4, hfA, b2, hB, 0);

    // head
    final_k<<<FB, 256, 0, stream>>>(hB, Wout, bout, out);
}

// Round 3
// 343.786 us; speedup vs baseline: 1.6480x; 1.2417x over previous
//
#include <hip/hip_runtime.h>
#include <cmath>

#define N_NODES 50000
#define N_EDGES 800000
#define NB_SCAN ((N_NODES + 255) / 256)   // 196
// IN_DIM = HEADS*HID = 128, HEADS=4, HID=32

typedef unsigned short u16;
typedef unsigned int u32;

static __device__ __forceinline__ float lrelu(float x) { return x > 0.f ? x : 0.2f * x; }
static __device__ __forceinline__ float bf2f(u16 u) { return __uint_as_float(((u32)u) << 16); }
static __device__ __forceinline__ u16 f2bf(float f) {
    u32 b = __float_as_uint(f);
    return (u16)((b + 0x7FFFu + ((b >> 16) & 1u)) >> 16);  // RNE
}

// ---------------- CSR build ----------------
__global__ __launch_bounds__(256) void count_k(const int* __restrict__ dst, int* __restrict__ cnt) {
    int e = blockIdx.x * 256 + threadIdx.x;
    if (e < N_EDGES) atomicAdd(&cnt[dst[e]], 1);
}

__global__ __launch_bounds__(256) void partial_k(const int* __restrict__ cnt, int* __restrict__ bsum) {
    int i = blockIdx.x * 256 + threadIdx.x;
    int v = (i < N_NODES) ? cnt[i] : 0;
#pragma unroll
    for (int o = 1; o < 64; o <<= 1) v += __shfl_xor(v, o);
    __shared__ int s[4];
    if ((threadIdx.x & 63) == 0) s[threadIdx.x >> 6] = v;
    __syncthreads();
    if (threadIdx.x == 0) bsum[blockIdx.x] = s[0] + s[1] + s[2] + s[3];
}

__global__ __launch_bounds__(256) void scanb_k(int* __restrict__ bsum) {
    __shared__ int s[256];
    int tid = threadIdx.x;
    int v = (tid < NB_SCAN) ? bsum[tid] : 0;
    s[tid] = v;
    __syncthreads();
    for (int o = 1; o < 256; o <<= 1) {
        int t = (tid >= o) ? s[tid - o] : 0;
        __syncthreads();
        s[tid] += t;
        __syncthreads();
    }
    if (tid < NB_SCAN) bsum[tid] = (tid == 0) ? 0 : s[tid - 1];
}

__global__ __launch_bounds__(256) void expand_k(const int* __restrict__ cnt, const int* __restrict__ bsum,
                                                int* __restrict__ offs, int* __restrict__ fillpos) {
    int i = blockIdx.x * 256 + threadIdx.x;
    int lane = threadIdx.x & 63, wid = threadIdx.x >> 6;
    int v = (i < N_NODES) ? cnt[i] : 0;
    int orig = v;
#pragma unroll
    for (int o = 1; o < 64; o <<= 1) {
        int t = __shfl_up(v, o);
        if (lane >= o) v += t;
    }
    __shared__ int ws[4];
    if (lane == 63) ws[wid] = v;
    __syncthreads();
    int woff = 0;
#pragma unroll
    for (int k = 0; k < 4; k++)
        if (k < wid) woff += ws[k];
    int ex = bsum[blockIdx.x] + woff + (v - orig);
    if (i < N_NODES) {
        offs[i] = ex;
        fillpos[i] = ex;
    }
    if (i == N_NODES - 1) offs[N_NODES] = ex + orig;
}

// fill: CSR payload is just the src node id (edge weights computed on the fly in agg)
__global__ __launch_bounds__(256) void fill_k(const int* __restrict__ src, const int* __restrict__ dst,
                                              int* __restrict__ fillpos, int* __restrict__ srcs) {
    int e = blockIdx.x * 256 + threadIdx.x;
    if (e >= N_EDGES) return;
    int d = dst[e];
    int pos = atomicAdd(&fillpos[d], 1);
    srcs[pos] = src[e];
}

// ---------------- GEMM (X[N,128] @ W[128,128]) fused with el/er head dots ----------------
// BF16IN: 0 = fp32 input X, 1 = bf16 input X. Output hf is bf16; el/er fp32.
template <int BF16IN>
__global__ __launch_bounds__(256) void gemm_attn(
    const void* __restrict__ Xv, const float* __restrict__ W,
    const float* __restrict__ al, const float* __restrict__ ar,
    u16* __restrict__ hf, float* __restrict__ el, float* __restrict__ er, int n)
{
    __shared__ float xs[64][128];
    int row0 = blockIdx.x * 64;
    int tid = threadIdx.x;
    if (BF16IN) {
        const u16* Xb = (const u16*)Xv;
        for (int i = tid; i < 64 * 32; i += 256) {
            int r = i >> 5, c4 = i & 31;
            float4 v = make_float4(0.f, 0.f, 0.f, 0.f);
            if (row0 + r < n) {
                ushort4 u = ((const ushort4*)(Xb + (size_t)(row0 + r) * 128))[c4];
                v = make_float4(bf2f(u.x), bf2f(u.y), bf2f(u.z), bf2f(u.w));
            }
            ((float4*)&xs[r][0])[c4] = v;
        }
    } else {
        const float4* X4 = (const float4*)Xv;
        for (int i = tid; i < 64 * 32; i += 256) {
            int r = i >> 5, c = i & 31;
            float4 v = make_float4(0.f, 0.f, 0.f, 0.f);
            if (row0 + r < n) v = X4[(size_t)(row0 + r) * 32 + c];
            ((float4*)&xs[r][0])[c] = v;
        }
    }
    __syncthreads();

    int tx = tid & 31;   // col4
    int ty = tid >> 5;   // 0..7
    float4 acc[8];
#pragma unroll
    for (int i = 0; i < 8; i++) acc[i] = make_float4(0.f, 0.f, 0.f, 0.f);

    const float4* W4 = (const float4*)W;
    for (int k4 = 0; k4 < 32; ++k4) {
        float4 w0 = W4[(4 * k4 + 0) * 32 + tx];
        float4 w1 = W4[(4 * k4 + 1) * 32 + tx];
        float4 w2 = W4[(4 * k4 + 2) * 32 + tx];
        float4 w3 = W4[(4 * k4 + 3) * 32 + tx];
#pragma unroll
        for (int i = 0; i < 8; i++) {
            float4 x = ((const float4*)&xs[ty + i * 8][0])[k4];
            acc[i].x += x.x * w0.x + x.y * w1.x + x.z * w2.x + x.w * w3.x;
            acc[i].y += x.x * w0.y + x.y * w1.y + x.z * w2.y + x.w * w3.y;
            acc[i].z += x.x * w0.z + x.y * w1.z + x.z * w2.z + x.w * w3.z;
            acc[i].w += x.x * w0.w + x.y * w1.w + x.z * w2.w + x.w * w3.w;
        }
    }

    int head = tx >> 3;
    int sub = tx & 7;
    float4 av = ((const float4*)al)[head * 8 + sub];
    float4 rv = ((const float4*)ar)[head * 8 + sub];
#pragma unroll
    for (int i = 0; i < 8; i++) {
        int row = row0 + ty + i * 8;
        float pel = acc[i].x * av.x + acc[i].y * av.y + acc[i].z * av.z + acc[i].w * av.w;
        float per = acc[i].x * rv.x + acc[i].y * rv.y + acc[i].z * rv.z + acc[i].w * rv.w;
        pel += __shfl_xor(pel, 1); pel += __shfl_xor(pel, 2); pel += __shfl_xor(pel, 4);
        per += __shfl_xor(per, 1); per += __shfl_xor(per, 2); per += __shfl_xor(per, 4);
        if (row < n) {
            ((ushort4*)hf)[(size_t)row * 32 + tx] =
                make_ushort4(f2bf(acc[i].x), f2bf(acc[i].y), f2bf(acc[i].z), f2bf(acc[i].w));
            if (sub == 0) {
                el[row * 4 + head] = pel;
                er[row * 4 + head] = per;
            }
        }
    }
}

// ---------------- layer-1 aggregation: on-the-fly softmax weights, bf16 in/out ----------------
__global__ __launch_bounds__(256) void agg1_k(const int* __restrict__ offs, const int* __restrict__ srcs,
                                              const float* __restrict__ el, const float* __restrict__ er,
                                              const ushort2* __restrict__ hfb, const float* __restrict__ bias,
                                              ushort2* __restrict__ h1) {
    int node = blockIdx.x * 4 + (threadIdx.x >> 6);
    int lane = threadIdx.x & 63;
    if (node >= N_NODES) return;
    int h = lane >> 4;
    float erh = er[node * 4 + h];
    int beg = offs[node], end = offs[node + 1];
    float ax = 0.f, ay = 0.f, den = 0.f;
    int j = beg;
    for (; j + 3 < end; j += 4) {
        int s0 = srcs[j], s1 = srcs[j + 1], s2 = srcs[j + 2], s3 = srcs[j + 3];
        float e0 = el[s0 * 4 + h], e1 = el[s1 * 4 + h], e2 = el[s2 * 4 + h], e3 = el[s3 * 4 + h];
        ushort2 u0 = hfb[(size_t)s0 * 64 + lane];
        ushort2 u1 = hfb[(size_t)s1 * 64 + lane];
        ushort2 u2 = hfb[(size_t)s2 * 64 + lane];
        ushort2 u3 = hfb[(size_t)s3 * 64 + lane];
        float w0 = __expf(lrelu(e0 + erh));
        float w1 = __expf(lrelu(e1 + erh));
        float w2 = __expf(lrelu(e2 + erh));
        float w3 = __expf(lrelu(e3 + erh));
        ax += w0 * bf2f(u0.x) + w1 * bf2f(u1.x) + w2 * bf2f(u2.x) + w3 * bf2f(u3.x);
        ay += w0 * bf2f(u0.y) + w1 * bf2f(u1.y) + w2 * bf2f(u2.y) + w3 * bf2f(u3.y);
        den += w0 + w1 + w2 + w3;
    }
    for (; j < end; ++j) {
        int s = srcs[j];
        float e = el[s * 4 + h];
        ushort2 u = hfb[(size_t)s * 64 + lane];
        float wv = __expf(lrelu(e + erh));
        ax += wv * bf2f(u.x);
        ay += wv * bf2f(u.y);
        den += wv;
    }
    float inv = 1.0f / fmaxf(den, 1e-30f);
    float o0 = fmaxf(ax * inv + bias[2 * lane], 0.f);
    float o1 = fmaxf(ay * inv + bias[2 * lane + 1], 0.f);
    h1[(size_t)node * 64 + lane] = make_ushort2(f2bf(o0), f2bf(o1));
}

// ---------------- layer-2 aggregation fused with head-mean/relu/proj/softmax ----------------
__global__ __launch_bounds__(256) void agg2_k(const int* __restrict__ offs, const int* __restrict__ srcs,
                                              const float* __restrict__ el, const float* __restrict__ er,
                                              const ushort2* __restrict__ hfb, const float* __restrict__ bias,
                                              const float* __restrict__ Wout, const float* __restrict__ bout,
                                              float2* __restrict__ out) {
    int node = blockIdx.x * 4 + (threadIdx.x >> 6);
    int lane = threadIdx.x & 63;
    if (node >= N_NODES) return;
    int h = lane >> 4;
    float erh = er[node * 4 + h];
    int beg = offs[node], end = offs[node + 1];
    float ax = 0.f, ay = 0.f, den = 0.f;
    int j = beg;
    for (; j + 3 < end; j += 4) {
        int s0 = srcs[j], s1 = srcs[j + 1], s2 = srcs[j + 2], s3 = srcs[j + 3];
        float e0 = el[s0 * 4 + h], e1 = el[s1 * 4 + h], e2 = el[s2 * 4 + h], e3 = el[s3 * 4 + h];
        ushort2 u0 = hfb[(size_t)s0 * 64 + lane];
        ushort2 u1 = hfb[(size_t)s1 * 64 + lane];
        ushort2 u2 = hfb[(size_t)s2 * 64 + lane];
        ushort2 u3 = hfb[(size_t)s3 * 64 + lane];
        float w0 = __expf(lrelu(e0 + erh));
        float w1 = __expf(lrelu(e1 + erh));
        float w2 = __expf(lrelu(e2 + erh));
        float w3 = __expf(lrelu(e3 + erh));
        ax += w0 * bf2f(u0.x) + w1 * bf2f(u1.x) + w2 * bf2f(u2.x) + w3 * bf2f(u3.x);
        ay += w0 * bf2f(u0.y) + w1 * bf2f(u1.y) + w2 * bf2f(u2.y) + w3 * bf2f(u3.y);
        den += w0 + w1 + w2 + w3;
    }
    for (; j < end; ++j) {
        int s = srcs[j];
        float e = el[s * 4 + h];
        ushort2 u = hfb[(size_t)s * 64 + lane];
        float wv = __expf(lrelu(e + erh));
        ax += wv * bf2f(u.x);
        ay += wv * bf2f(u.y);
        den += wv;
    }
    float inv = 1.0f / fmaxf(den, 1e-30f);
    float o0 = ax * inv + bias[2 * lane];
    float o1 = ay * inv + bias[2 * lane + 1];
    // head mean: sum lanes {l, l^16, l^32, l^48}
    o0 += __shfl_xor(o0, 16); o0 += __shfl_xor(o0, 32);
    o1 += __shfl_xor(o1, 16); o1 += __shfl_xor(o1, 32);
    float r0 = fmaxf(0.25f * o0, 0.f);
    float r1 = fmaxf(0.25f * o1, 0.f);
    int d0 = (lane & 15) * 2;
    float l0 = r0 * Wout[d0 * 2] + r1 * Wout[(d0 + 1) * 2];
    float l1 = r0 * Wout[d0 * 2 + 1] + r1 * Wout[(d0 + 1) * 2 + 1];
#pragma unroll
    for (int o = 1; o < 16; o <<= 1) {
        l0 += __shfl_xor(l0, o);
        l1 += __shfl_xor(l1, o);
    }
    if (lane == 0) {
        l0 += bout[0];
        l1 += bout[1];
        float mx = fmaxf(l0, l1);
        float e0 = __expf(l0 - mx), e1 = __expf(l1 - mx);
        float invs = 1.f / (e0 + e1);
        out[node] = make_float2(e0 * invs, e1 * invs);
    }
}

extern "C" void kernel_launch(void* const* d_in, const int* in_sizes, int n_in,
                              void* d_out, int out_size, void* d_ws, size_t ws_size,
                              hipStream_t stream) {
    const float* in_feat = (const float*)d_in[0];
    const float* W1   = (const float*)d_in[1];
    const float* al1  = (const float*)d_in[2];
    const float* ar1  = (const float*)d_in[3];
    const float* b1   = (const float*)d_in[4];
    const float* W2   = (const float*)d_in[5];
    const float* al2  = (const float*)d_in[6];
    const float* ar2  = (const float*)d_in[7];
    const float* b2   = (const float*)d_in[8];
    const float* Wout = (const float*)d_in[9];
    const float* bout = (const float*)d_in[10];
    const int*   src  = (const int*)d_in[11];
    const int*   dst  = (const int*)d_in[12];
    float* out = (float*)d_out;

    char* ws = (char*)d_ws;
    size_t off = 0;
    auto carve = [&](size_t bytes) {
        char* p = ws + off;
        off = (off + bytes + 255) & ~(size_t)255;
        return p;
    };
    u16*   hfA   = (u16*)carve((size_t)N_NODES * 128 * 2);   // hf (bf16), both layers
    u16*   h1    = (u16*)carve((size_t)N_NODES * 128 * 2);   // relu output of layer 1 (bf16)
    float* el    = (float*)carve((size_t)N_NODES * 4 * 4);
    float* er    = (float*)carve((size_t)N_NODES * 4 * 4);
    int*   srcs  = (int*)carve((size_t)N_EDGES * 4);
    int*   cnt   = (int*)carve((size_t)N_NODES * 4);
    int*   offs  = (int*)carve((size_t)(N_NODES + 1) * 4);
    int*   fillp = (int*)carve((size_t)N_NODES * 4);
    int*   bsum  = (int*)carve((size_t)NB_SCAN * 4);
    (void)ws_size; (void)in_sizes; (void)n_in; (void)out_size;

    const int EB = (N_EDGES + 255) / 256;        // 3125
    const int GB = (N_NODES + 63) / 64;          // 782
    const int AB = (N_NODES + 3) / 4;            // 12500

    // CSR build (shared by both layers)
    hipMemsetAsync(cnt, 0, (size_t)N_NODES * 4, stream);
    count_k<<<EB, 256, 0, stream>>>(dst, cnt);
    partial_k<<<NB_SCAN, 256, 0, stream>>>(cnt, bsum);
    scanb_k<<<1, 256, 0, stream>>>(bsum);
    expand_k<<<NB_SCAN, 256, 0, stream>>>(cnt, bsum, offs, fillp);
    fill_k<<<EB, 256, 0, stream>>>(src, dst, fillp, srcs);

    // layer 1
    gemm_attn<0><<<GB, 256, 0, stream>>>(in_feat, W1, al1, ar1, hfA, el, er, N_NODES);
    agg1_k<<<AB, 256, 0, stream>>>(offs, srcs, el, er, (const ushort2*)hfA, b1, (ushort2*)h1);

    // layer 2
    gemm_attn<1><<<GB, 256, 0, stream>>>(h1, W2, al2, ar2, hfA, el, er, N_NODES);
    agg2_k<<<AB, 256, 0, stream>>>(offs, srcs, el, er, (const ushort2*)hfA, b2, Wout, bout, (float2*)out);
}

// Round 4
// 334.431 us; speedup vs baseline: 1.6941x; 1.0280x over previous
//
#include <hip/hip_runtime.h>
#include <cmath>

#define N_NODES 50000
#define N_EDGES 800000
#define NB_SCAN ((N_NODES + 255) / 256)   // 196
// IN_DIM = HEADS*HID = 128, HEADS=4, HID=32

typedef unsigned short u16;
typedef unsigned int u32;

static __device__ __forceinline__ float lrelu(float x) { return x > 0.f ? x : 0.2f * x; }
static __device__ __forceinline__ float bf2f(u16 u) { return __uint_as_float(((u32)u) << 16); }
static __device__ __forceinline__ float bflo(u32 u) { return __uint_as_float(u << 16); }
static __device__ __forceinline__ float bfhi(u32 u) { return __uint_as_float(u & 0xFFFF0000u); }
static __device__ __forceinline__ u16 f2bf(float f) {
    u32 b = __float_as_uint(f);
    return (u16)((b + 0x7FFFu + ((b >> 16) & 1u)) >> 16);  // RNE
}
static __device__ __forceinline__ u32 pack2(float a, float b) {
    return (u32)f2bf(a) | ((u32)f2bf(b) << 16);
}

// ---------------- CSR build ----------------
__global__ __launch_bounds__(256) void count_k(const int* __restrict__ dst, int* __restrict__ cnt) {
    int e = blockIdx.x * 256 + threadIdx.x;
    if (e < N_EDGES) atomicAdd(&cnt[dst[e]], 1);
}

__global__ __launch_bounds__(256) void partial_k(const int* __restrict__ cnt, int* __restrict__ bsum) {
    int i = blockIdx.x * 256 + threadIdx.x;
    int v = (i < N_NODES) ? cnt[i] : 0;
#pragma unroll
    for (int o = 1; o < 64; o <<= 1) v += __shfl_xor(v, o);
    __shared__ int s[4];
    if ((threadIdx.x & 63) == 0) s[threadIdx.x >> 6] = v;
    __syncthreads();
    if (threadIdx.x == 0) bsum[blockIdx.x] = s[0] + s[1] + s[2] + s[3];
}

__global__ __launch_bounds__(256) void scanb_k(int* __restrict__ bsum) {
    __shared__ int s[256];
    int tid = threadIdx.x;
    int v = (tid < NB_SCAN) ? bsum[tid] : 0;
    s[tid] = v;
    __syncthreads();
    for (int o = 1; o < 256; o <<= 1) {
        int t = (tid >= o) ? s[tid - o] : 0;
        __syncthreads();
        s[tid] += t;
        __syncthreads();
    }
    if (tid < NB_SCAN) bsum[tid] = (tid == 0) ? 0 : s[tid - 1];
}

__global__ __launch_bounds__(256) void expand_k(const int* __restrict__ cnt, const int* __restrict__ bsum,
                                                int* __restrict__ offs, int* __restrict__ fillpos) {
    int i = blockIdx.x * 256 + threadIdx.x;
    int lane = threadIdx.x & 63, wid = threadIdx.x >> 6;
    int v = (i < N_NODES) ? cnt[i] : 0;
    int orig = v;
#pragma unroll
    for (int o = 1; o < 64; o <<= 1) {
        int t = __shfl_up(v, o);
        if (lane >= o) v += t;
    }
    __shared__ int ws[4];
    if (lane == 63) ws[wid] = v;
    __syncthreads();
    int woff = 0;
#pragma unroll
    for (int k = 0; k < 4; k++)
        if (k < wid) woff += ws[k];
    int ex = bsum[blockIdx.x] + woff + (v - orig);
    if (i < N_NODES) {
        offs[i] = ex;
        fillpos[i] = ex;
    }
    if (i == N_NODES - 1) offs[N_NODES] = ex + orig;
}

__global__ __launch_bounds__(256) void fill_k(const int* __restrict__ src, const int* __restrict__ dst,
                                              int* __restrict__ fillpos, int* __restrict__ srcs) {
    int e = blockIdx.x * 256 + threadIdx.x;
    if (e >= N_EDGES) return;
    int d = dst[e];
    int pos = atomicAdd(&fillpos[d], 1);
    srcs[pos] = src[e];
}

// ---------------- GEMM (X[N,128] @ W[128,128]) fused with el/er head dots ----------------
template <int BF16IN>
__global__ __launch_bounds__(256) void gemm_attn(
    const void* __restrict__ Xv, const float* __restrict__ W,
    const float* __restrict__ al, const float* __restrict__ ar,
    u16* __restrict__ hf, float* __restrict__ el, float* __restrict__ er, int n)
{
    __shared__ float xs[64][128];
    int row0 = blockIdx.x * 64;
    int tid = threadIdx.x;
    if (BF16IN) {
        const u16* Xb = (const u16*)Xv;
        for (int i = tid; i < 64 * 32; i += 256) {
            int r = i >> 5, c4 = i & 31;
            float4 v = make_float4(0.f, 0.f, 0.f, 0.f);
            if (row0 + r < n) {
                ushort4 u = ((const ushort4*)(Xb + (size_t)(row0 + r) * 128))[c4];
                v = make_float4(bf2f(u.x), bf2f(u.y), bf2f(u.z), bf2f(u.w));
            }
            ((float4*)&xs[r][0])[c4] = v;
        }
    } else {
        const float4* X4 = (const float4*)Xv;
        for (int i = tid; i < 64 * 32; i += 256) {
            int r = i >> 5, c = i & 31;
            float4 v = make_float4(0.f, 0.f, 0.f, 0.f);
            if (row0 + r < n) v = X4[(size_t)(row0 + r) * 32 + c];
            ((float4*)&xs[r][0])[c] = v;
        }
    }
    __syncthreads();

    int tx = tid & 31;   // col4
    int ty = tid >> 5;   // 0..7
    float4 acc[8];
#pragma unroll
    for (int i = 0; i < 8; i++) acc[i] = make_float4(0.f, 0.f, 0.f, 0.f);

    const float4* W4 = (const float4*)W;
    for (int k4 = 0; k4 < 32; ++k4) {
        float4 w0 = W4[(4 * k4 + 0) * 32 + tx];
        float4 w1 = W4[(4 * k4 + 1) * 32 + tx];
        float4 w2 = W4[(4 * k4 + 2) * 32 + tx];
        float4 w3 = W4[(4 * k4 + 3) * 32 + tx];
#pragma unroll
        for (int i = 0; i < 8; i++) {
            float4 x = ((const float4*)&xs[ty + i * 8][0])[k4];
            acc[i].x += x.x * w0.x + x.y * w1.x + x.z * w2.x + x.w * w3.x;
            acc[i].y += x.x * w0.y + x.y * w1.y + x.z * w2.y + x.w * w3.y;
            acc[i].z += x.x * w0.z + x.y * w1.z + x.z * w2.z + x.w * w3.z;
            acc[i].w += x.x * w0.w + x.y * w1.w + x.z * w2.w + x.w * w3.w;
        }
    }

    int head = tx >> 3;
    int sub = tx & 7;
    float4 av = ((const float4*)al)[head * 8 + sub];
    float4 rv = ((const float4*)ar)[head * 8 + sub];
#pragma unroll
    for (int i = 0; i < 8; i++) {
        int row = row0 + ty + i * 8;
        float pel = acc[i].x * av.x + acc[i].y * av.y + acc[i].z * av.z + acc[i].w * av.w;
        float per = acc[i].x * rv.x + acc[i].y * rv.y + acc[i].z * rv.z + acc[i].w * rv.w;
        pel += __shfl_xor(pel, 1); pel += __shfl_xor(pel, 2); pel += __shfl_xor(pel, 4);
        per += __shfl_xor(per, 1); per += __shfl_xor(per, 2); per += __shfl_xor(per, 4);
        if (row < n) {
            ((ushort4*)hf)[(size_t)row * 32 + tx] =
                make_ushort4(f2bf(acc[i].x), f2bf(acc[i].y), f2bf(acc[i].z), f2bf(acc[i].w));
            if (sub == 0) {
                el[row * 4 + head] = pel;
                er[row * 4 + head] = per;
            }
        }
    }
}

// ---------------- agg core: quarter-wave per edge, lane owns 8 features (uint4 of bf16) ---------
// lane = qw*16 + q; quarter qw handles edges beg+4k+qw; lane features f = q*8..q*8+7, head = q>>2.
static __device__ __forceinline__ void agg_core(
    int node, int lane, const int* __restrict__ offs, const int* __restrict__ srcs,
    const float* __restrict__ el, const float* __restrict__ er, const u16* __restrict__ hf,
    float acc[8], float& den)
{
    int qw = lane >> 4;
    int q = lane & 15;
    int h = q >> 2;
    float erh = er[node * 4 + h];
    int beg = offs[node], end = offs[node + 1];
    den = 0.f;
#pragma unroll
    for (int i = 0; i < 8; i++) acc[i] = 0.f;
    int base = beg;
    for (; base + 8 <= end; base += 8) {
        int s0 = srcs[base + qw];
        int s1 = srcs[base + 4 + qw];
        float w0 = __expf(lrelu(el[s0 * 4 + h] + erh));
        float w1 = __expf(lrelu(el[s1 * 4 + h] + erh));
        uint4 u0 = *(const uint4*)(hf + (size_t)s0 * 128 + q * 8);
        uint4 u1 = *(const uint4*)(hf + (size_t)s1 * 128 + q * 8);
        den += w0 + w1;
        acc[0] += w0 * bflo(u0.x) + w1 * bflo(u1.x);
        acc[1] += w0 * bfhi(u0.x) + w1 * bfhi(u1.x);
        acc[2] += w0 * bflo(u0.y) + w1 * bflo(u1.y);
        acc[3] += w0 * bfhi(u0.y) + w1 * bfhi(u1.y);
        acc[4] += w0 * bflo(u0.z) + w1 * bflo(u1.z);
        acc[5] += w0 * bfhi(u0.z) + w1 * bfhi(u1.z);
        acc[6] += w0 * bflo(u0.w) + w1 * bflo(u1.w);
        acc[7] += w0 * bfhi(u0.w) + w1 * bfhi(u1.w);
    }
    for (; base < end; base += 4) {
        int e = base + qw;
        bool valid = e < end;
        int ec = valid ? e : end - 1;
        int s = srcs[ec];
        float w = valid ? __expf(lrelu(el[s * 4 + h] + erh)) : 0.f;
        uint4 u = *(const uint4*)(hf + (size_t)s * 128 + q * 8);
        den += w;
        acc[0] += w * bflo(u.x);
        acc[1] += w * bfhi(u.x);
        acc[2] += w * bflo(u.y);
        acc[3] += w * bfhi(u.y);
        acc[4] += w * bflo(u.z);
        acc[5] += w * bfhi(u.z);
        acc[6] += w * bflo(u.w);
        acc[7] += w * bfhi(u.w);
    }
    // reduce across the 4 quarters (lane bits 4,5)
#pragma unroll
    for (int i = 0; i < 8; i++) {
        acc[i] += __shfl_xor(acc[i], 16);
        acc[i] += __shfl_xor(acc[i], 32);
    }
    den += __shfl_xor(den, 16);
    den += __shfl_xor(den, 32);
}

// ---------------- layer-1 aggregation (relu, bf16 out) ----------------
__global__ __launch_bounds__(256) void agg1_k(const int* __restrict__ offs, const int* __restrict__ srcs,
                                              const float* __restrict__ el, const float* __restrict__ er,
                                              const u16* __restrict__ hf, const float* __restrict__ bias,
                                              u16* __restrict__ h1) {
    int node = blockIdx.x * 4 + (threadIdx.x >> 6);
    int lane = threadIdx.x & 63;
    if (node >= N_NODES) return;
    float acc[8], den;
    agg_core(node, lane, offs, srcs, el, er, hf, acc, den);
    int qw = lane >> 4, q = lane & 15;
    if (qw == 0) {
        float inv = 1.0f / fmaxf(den, 1e-30f);
        float o[8];
#pragma unroll
        for (int i = 0; i < 8; i++)
            o[i] = fmaxf(acc[i] * inv + bias[q * 8 + i], 0.f);
        uint4 pk;
        pk.x = pack2(o[0], o[1]);
        pk.y = pack2(o[2], o[3]);
        pk.z = pack2(o[4], o[5]);
        pk.w = pack2(o[6], o[7]);
        *(uint4*)(h1 + (size_t)node * 128 + q * 8) = pk;
    }
}

// ---------------- layer-2 aggregation fused with head-mean/relu/proj/softmax ----------------
__global__ __launch_bounds__(256) void agg2_k(const int* __restrict__ offs, const int* __restrict__ srcs,
                                              const float* __restrict__ el, const float* __restrict__ er,
                                              const u16* __restrict__ hf, const float* __restrict__ bias,
                                              const float* __restrict__ Wout, const float* __restrict__ bout,
                                              float2* __restrict__ out) {
    int node = blockIdx.x * 4 + (threadIdx.x >> 6);
    int lane = threadIdx.x & 63;
    if (node >= N_NODES) return;
    float acc[8], den;
    agg_core(node, lane, offs, srcs, el, er, hf, acc, den);
    int q = lane & 15;
    float inv = 1.0f / fmaxf(den, 1e-30f);
    float o[8];
#pragma unroll
    for (int i = 0; i < 8; i++) o[i] = acc[i] * inv + bias[q * 8 + i];
    // mean over heads: head index lives in lane bits 2,3
#pragma unroll
    for (int i = 0; i < 8; i++) {
        o[i] += __shfl_xor(o[i], 4);
        o[i] += __shfl_xor(o[i], 8);
        o[i] = fmaxf(0.25f * o[i], 0.f);
    }
    int d0 = (q & 3) * 8;
    float l0 = 0.f, l1 = 0.f;
#pragma unroll
    for (int i = 0; i < 8; i++) {
        l0 += o[i] * Wout[(d0 + i) * 2];
        l1 += o[i] * Wout[(d0 + i) * 2 + 1];
    }
    l0 += __shfl_xor(l0, 1); l0 += __shfl_xor(l0, 2);
    l1 += __shfl_xor(l1, 1); l1 += __shfl_xor(l1, 2);
    if (lane == 0) {
        l0 += bout[0];
        l1 += bout[1];
        float mx = fmaxf(l0, l1);
        float e0 = __expf(l0 - mx), e1 = __expf(l1 - mx);
        float invs = 1.f / (e0 + e1);
        out[node] = make_float2(e0 * invs, e1 * invs);
    }
}

extern "C" void kernel_launch(void* const* d_in, const int* in_sizes, int n_in,
                              void* d_out, int out_size, void* d_ws, size_t ws_size,
                              hipStream_t stream) {
    const float* in_feat = (const float*)d_in[0];
    const float* W1   = (const float*)d_in[1];
    const float* al1  = (const float*)d_in[2];
    const float* ar1  = (const float*)d_in[3];
    const float* b1   = (const float*)d_in[4];
    const float* W2   = (const float*)d_in[5];
    const float* al2  = (const float*)d_in[6];
    const float* ar2  = (const float*)d_in[7];
    const float* b2   = (const float*)d_in[8];
    const float* Wout = (const float*)d_in[9];
    const float* bout = (const float*)d_in[10];
    const int*   src  = (const int*)d_in[11];
    const int*   dst  = (const int*)d_in[12];
    float* out = (float*)d_out;

    char* ws = (char*)d_ws;
    size_t off = 0;
    auto carve = [&](size_t bytes) {
        char* p = ws + off;
        off = (off + bytes + 255) & ~(size_t)255;
        return p;
    };
    u16*   hfA   = (u16*)carve((size_t)N_NODES * 128 * 2);
    u16*   h1    = (u16*)carve((size_t)N_NODES * 128 * 2);
    float* el    = (float*)carve((size_t)N_NODES * 4 * 4);
    float* er    = (float*)carve((size_t)N_NODES * 4 * 4);
    int*   srcs  = (int*)carve((size_t)N_EDGES * 4);
    int*   cnt   = (int*)carve((size_t)N_NODES * 4);
    int*   offs  = (int*)carve((size_t)(N_NODES + 1) * 4);
    int*   fillp = (int*)carve((size_t)N_NODES * 4);
    int*   bsum  = (int*)carve((size_t)NB_SCAN * 4);
    (void)ws_size; (void)in_sizes; (void)n_in; (void)out_size;

    const int EB = (N_EDGES + 255) / 256;        // 3125
    const int GB = (N_NODES + 63) / 64;          // 782
    const int AB = (N_NODES + 3) / 4;            // 12500

    // CSR build (shared by both layers)
    hipMemsetAsync(cnt, 0, (size_t)N_NODES * 4, stream);
    count_k<<<EB, 256, 0, stream>>>(dst, cnt);
    partial_k<<<NB_SCAN, 256, 0, stream>>>(cnt, bsum);
    scanb_k<<<1, 256, 0, stream>>>(bsum);
    expand_k<<<NB_SCAN, 256, 0, stream>>>(cnt, bsum, offs, fillp);
    fill_k<<<EB, 256, 0, stream>>>(src, dst, fillp, srcs);

    // layer 1
    gemm_attn<0><<<GB, 256, 0, stream>>>(in_feat, W1, al1, ar1, hfA, el, er, N_NODES);
    agg1_k<<<AB, 256, 0, stream>>>(offs, srcs, el, er, hfA, b1, h1);

    // layer 2
    gemm_attn<1><<<GB, 256, 0, stream>>>(h1, W2, al2, ar2, hfA, el, er, N_NODES);
    agg2_k<<<AB, 256, 0, stream>>>(offs, srcs, el, er, hfA, b2, Wout, bout, (float2*)out);
}

// Round 5
// 266.380 us; speedup vs baseline: 2.1269x; 1.2555x over previous
//
#include <hip/hip_runtime.h>
#include <cmath>

#define N_NODES 50000
#define N_EDGES 800000
#define NBUCK 196          // buckets of 256 nodes: bucket = dst >> 8
#define NHB 196            // histogram blocks, 4096 edges each
#define EPB 4096
// IN_DIM = HEADS*HID = 128, HEADS=4, HID=32

typedef unsigned short u16;
typedef unsigned int u32;

static __device__ __forceinline__ float lrelu(float x) { return x > 0.f ? x : 0.2f * x; }
static __device__ __forceinline__ float bf2f(u16 u) { return __uint_as_float(((u32)u) << 16); }
static __device__ __forceinline__ float bflo(u32 u) { return __uint_as_float(u << 16); }
static __device__ __forceinline__ float bfhi(u32 u) { return __uint_as_float(u & 0xFFFF0000u); }
static __device__ __forceinline__ u16 f2bf(float f) {
    u32 b = __float_as_uint(f);
    return (u16)((b + 0x7FFFu + ((b >> 16) & 1u)) >> 16);  // RNE
}
static __device__ __forceinline__ u32 pack2(float a, float b) {
    return (u32)f2bf(a) | ((u32)f2bf(b) << 16);
}

// ---------------- bucketed CSR build ----------------
// 1) per-block histogram over 196 coarse buckets
__global__ __launch_bounds__(1024) void bhist_k(const int* __restrict__ dst, u32* __restrict__ bcnt) {
    __shared__ u32 hist[NBUCK];
    int tid = threadIdx.x;
    for (int i = tid; i < NBUCK; i += 1024) hist[i] = 0;
    __syncthreads();
    int base = blockIdx.x * EPB;
#pragma unroll
    for (int k = 0; k < 4; ++k) {
        int e = base + k * 1024 + tid;
        if (e < N_EDGES) atomicAdd(&hist[dst[e] >> 8], 1u);
    }
    __syncthreads();
    for (int i = tid; i < NBUCK; i += 1024) bcnt[(size_t)blockIdx.x * NBUCK + i] = hist[i];
}

// 2) cross-block per-bucket exclusive offsets + bucket starts
__global__ __launch_bounds__(256) void bscan_k(const u32* __restrict__ bcnt, u32* __restrict__ wbase,
                                               int* __restrict__ bstart) {
    __shared__ int s[256];
    int t = threadIdx.x;
    u32 run = 0;
    if (t < NBUCK) {
        for (int blk = 0; blk < NHB; ++blk) {
            u32 v = bcnt[(size_t)blk * NBUCK + t];   // coalesced across t
            wbase[(size_t)blk * NBUCK + t] = run;
            run += v;
        }
    }
    s[t] = (t < NBUCK) ? (int)run : 0;
    __syncthreads();
    for (int o = 1; o < 256; o <<= 1) {
        int v = (t >= o) ? s[t - o] : 0;
        __syncthreads();
        s[t] += v;
        __syncthreads();
    }
    if (t < NBUCK) bstart[t] = (t == 0) ? 0 : s[t - 1];
    if (t == NBUCK - 1) bstart[NBUCK] = s[t];   // = N_EDGES
}

// 3) scatter edges into bucket-contiguous array; payload = src(16b) | dst_low8(<<16)
__global__ __launch_bounds__(1024) void bscatter_k(const int* __restrict__ src, const int* __restrict__ dst,
                                                   const u32* __restrict__ wbase, const int* __restrict__ bstart,
                                                   u32* __restrict__ bucketed) {
    __shared__ u32 pos[NBUCK];
    int tid = threadIdx.x;
    for (int i = tid; i < NBUCK; i += 1024)
        pos[i] = (u32)bstart[i] + wbase[(size_t)blockIdx.x * NBUCK + i];
    __syncthreads();
    int base = blockIdx.x * EPB;
#pragma unroll
    for (int k = 0; k < 4; ++k) {
        int e = base + k * 1024 + tid;
        if (e < N_EDGES) {
            int d = dst[e];
            int b = d >> 8;
            u32 p = atomicAdd(&pos[b], 1u);
            bucketed[p] = (u32)src[e] | ((u32)(d & 255) << 16);
        }
    }
}

// 4) per-bucket fine CSR: node offs + u16 srcs, all scatter confined to an 8 KB window
__global__ __launch_bounds__(256) void bcsr_k(const u32* __restrict__ bucketed, const int* __restrict__ bstart,
                                              int* __restrict__ offs, u16* __restrict__ srcs) {
    __shared__ u32 cnt[256];
    __shared__ int s[256];
    __shared__ u32 fp[256];
    int b = blockIdx.x;
    int tid = threadIdx.x;
    int ebeg = bstart[b], eend = bstart[b + 1];
    int ne = eend - ebeg;
    cnt[tid] = 0;
    __syncthreads();
    for (int i = tid; i < ne; i += 256)
        atomicAdd(&cnt[bucketed[ebeg + i] >> 16], 1u);
    __syncthreads();
    s[tid] = (int)cnt[tid];
    __syncthreads();
    for (int o = 1; o < 256; o <<= 1) {
        int v = (tid >= o) ? s[tid - o] : 0;
        __syncthreads();
        s[tid] += v;
        __syncthreads();
    }
    int excl = s[tid] - (int)cnt[tid];
    int node = b * 256 + tid;
    if (node < N_NODES) offs[node] = ebeg + excl;
    if (b == NBUCK - 1 && tid == 0) offs[N_NODES] = N_EDGES;
    fp[tid] = (u32)excl;
    __syncthreads();
    for (int i = tid; i < ne; i += 256) {
        u32 u = bucketed[ebeg + i];
        u32 p = atomicAdd(&fp[u >> 16], 1u);
        srcs[ebeg + p] = (u16)(u & 0xFFFFu);
    }
}

// ---------------- GEMM (X[N,128] @ W[128,128]) fused with el/er head dots ----------------
template <int BF16IN>
__global__ __launch_bounds__(256) void gemm_attn(
    const void* __restrict__ Xv, const float* __restrict__ W,
    const float* __restrict__ al, const float* __restrict__ ar,
    u16* __restrict__ hf, float* __restrict__ el, float* __restrict__ er, int n)
{
    __shared__ float xs[64][128];
    int row0 = blockIdx.x * 64;
    int tid = threadIdx.x;
    if (BF16IN) {
        const u16* Xb = (const u16*)Xv;
        for (int i = tid; i < 64 * 32; i += 256) {
            int r = i >> 5, c4 = i & 31;
            float4 v = make_float4(0.f, 0.f, 0.f, 0.f);
            if (row0 + r < n) {
                ushort4 u = ((const ushort4*)(Xb + (size_t)(row0 + r) * 128))[c4];
                v = make_float4(bf2f(u.x), bf2f(u.y), bf2f(u.z), bf2f(u.w));
            }
            ((float4*)&xs[r][0])[c4] = v;
        }
    } else {
        const float4* X4 = (const float4*)Xv;
        for (int i = tid; i < 64 * 32; i += 256) {
            int r = i >> 5, c = i & 31;
            float4 v = make_float4(0.f, 0.f, 0.f, 0.f);
            if (row0 + r < n) v = X4[(size_t)(row0 + r) * 32 + c];
            ((float4*)&xs[r][0])[c] = v;
        }
    }
    __syncthreads();

    int tx = tid & 31;   // col4
    int ty = tid >> 5;   // 0..7
    float4 acc[8];
#pragma unroll
    for (int i = 0; i < 8; i++) acc[i] = make_float4(0.f, 0.f, 0.f, 0.f);

    const float4* W4 = (const float4*)W;
    for (int k4 = 0; k4 < 32; ++k4) {
        float4 w0 = W4[(4 * k4 + 0) * 32 + tx];
        float4 w1 = W4[(4 * k4 + 1) * 32 + tx];
        float4 w2 = W4[(4 * k4 + 2) * 32 + tx];
        float4 w3 = W4[(4 * k4 + 3) * 32 + tx];
#pragma unroll
        for (int i = 0; i < 8; i++) {
            float4 x = ((const float4*)&xs[ty + i * 8][0])[k4];
            acc[i].x += x.x * w0.x + x.y * w1.x + x.z * w2.x + x.w * w3.x;
            acc[i].y += x.x * w0.y + x.y * w1.y + x.z * w2.y + x.w * w3.y;
            acc[i].z += x.x * w0.z + x.y * w1.z + x.z * w2.z + x.w * w3.z;
            acc[i].w += x.x * w0.w + x.y * w1.w + x.z * w2.w + x.w * w3.w;
        }
    }

    int head = tx >> 3;
    int sub = tx & 7;
    float4 av = ((const float4*)al)[head * 8 + sub];
    float4 rv = ((const float4*)ar)[head * 8 + sub];
#pragma unroll
    for (int i = 0; i < 8; i++) {
        int row = row0 + ty + i * 8;
        float pel = acc[i].x * av.x + acc[i].y * av.y + acc[i].z * av.z + acc[i].w * av.w;
        float per = acc[i].x * rv.x + acc[i].y * rv.y + acc[i].z * rv.z + acc[i].w * rv.w;
        pel += __shfl_xor(pel, 1); pel += __shfl_xor(pel, 2); pel += __shfl_xor(pel, 4);
        per += __shfl_xor(per, 1); per += __shfl_xor(per, 2); per += __shfl_xor(per, 4);
        if (row < n) {
            ((ushort4*)hf)[(size_t)row * 32 + tx] =
                make_ushort4(f2bf(acc[i].x), f2bf(acc[i].y), f2bf(acc[i].z), f2bf(acc[i].w));
            if (sub == 0) {
                el[row * 4 + head] = pel;
                er[row * 4 + head] = per;
            }
        }
    }
}

// ---------------- agg core: quarter-wave per edge, lane owns 8 features (uint4 of bf16) ---------
static __device__ __forceinline__ void agg_core(
    int node, int lane, const int* __restrict__ offs, const u16* __restrict__ srcs,
    const float* __restrict__ el, const float* __restrict__ er, const u16* __restrict__ hf,
    float acc[8], float& den)
{
    int qw = lane >> 4;
    int q = lane & 15;
    int h = q >> 2;
    float erh = er[node * 4 + h];
    int beg = offs[node], end = offs[node + 1];
    den = 0.f;
#pragma unroll
    for (int i = 0; i < 8; i++) acc[i] = 0.f;
    int base = beg;
    for (; base + 8 <= end; base += 8) {
        int s0 = srcs[base + qw];
        int s1 = srcs[base + 4 + qw];
        float w0 = __expf(lrelu(el[s0 * 4 + h] + erh));
        float w1 = __expf(lrelu(el[s1 * 4 + h] + erh));
        uint4 u0 = *(const uint4*)(hf + (size_t)s0 * 128 + q * 8);
        uint4 u1 = *(const uint4*)(hf + (size_t)s1 * 128 + q * 8);
        den += w0 + w1;
        acc[0] += w0 * bflo(u0.x) + w1 * bflo(u1.x);
        acc[1] += w0 * bfhi(u0.x) + w1 * bfhi(u1.x);
        acc[2] += w0 * bflo(u0.y) + w1 * bflo(u1.y);
        acc[3] += w0 * bfhi(u0.y) + w1 * bfhi(u1.y);
        acc[4] += w0 * bflo(u0.z) + w1 * bflo(u1.z);
        acc[5] += w0 * bfhi(u0.z) + w1 * bfhi(u1.z);
        acc[6] += w0 * bflo(u0.w) + w1 * bflo(u1.w);
        acc[7] += w0 * bfhi(u0.w) + w1 * bfhi(u1.w);
    }
    for (; base < end; base += 4) {
        int e = base + qw;
        bool valid = e < end;
        int ec = valid ? e : end - 1;
        int s = srcs[ec];
        float w = valid ? __expf(lrelu(el[s * 4 + h] + erh)) : 0.f;
        uint4 u = *(const uint4*)(hf + (size_t)s * 128 + q * 8);
        den += w;
        acc[0] += w * bflo(u.x);
        acc[1] += w * bfhi(u.x);
        acc[2] += w * bflo(u.y);
        acc[3] += w * bfhi(u.y);
        acc[4] += w * bflo(u.z);
        acc[5] += w * bfhi(u.z);
        acc[6] += w * bflo(u.w);
        acc[7] += w * bfhi(u.w);
    }
#pragma unroll
    for (int i = 0; i < 8; i++) {
        acc[i] += __shfl_xor(acc[i], 16);
        acc[i] += __shfl_xor(acc[i], 32);
    }
    den += __shfl_xor(den, 16);
    den += __shfl_xor(den, 32);
}

// ---------------- layer-1 aggregation (relu, bf16 out) ----------------
__global__ __launch_bounds__(256) void agg1_k(const int* __restrict__ offs, const u16* __restrict__ srcs,
                                              const float* __restrict__ el, const float* __restrict__ er,
                                              const u16* __restrict__ hf, const float* __restrict__ bias,
                                              u16* __restrict__ h1) {
    int node = blockIdx.x * 4 + (threadIdx.x >> 6);
    int lane = threadIdx.x & 63;
    if (node >= N_NODES) return;
    float acc[8], den;
    agg_core(node, lane, offs, srcs, el, er, hf, acc, den);
    int qw = lane >> 4, q = lane & 15;
    if (qw == 0) {
        float inv = 1.0f / fmaxf(den, 1e-30f);
        float o[8];
#pragma unroll
        for (int i = 0; i < 8; i++)
            o[i] = fmaxf(acc[i] * inv + bias[q * 8 + i], 0.f);
        uint4 pk;
        pk.x = pack2(o[0], o[1]);
        pk.y = pack2(o[2], o[3]);
        pk.z = pack2(o[4], o[5]);
        pk.w = pack2(o[6], o[7]);
        *(uint4*)(h1 + (size_t)node * 128 + q * 8) = pk;
    }
}

// ---------------- layer-2 aggregation fused with head-mean/relu/proj/softmax ----------------
__global__ __launch_bounds__(256) void agg2_k(const int* __restrict__ offs, const u16* __restrict__ srcs,
                                              const float* __restrict__ el, const float* __restrict__ er,
                                              const u16* __restrict__ hf, const float* __restrict__ bias,
                                              const float* __restrict__ Wout, const float* __restrict__ bout,
                                              float2* __restrict__ out) {
    int node = blockIdx.x * 4 + (threadIdx.x >> 6);
    int lane = threadIdx.x & 63;
    if (node >= N_NODES) return;
    float acc[8], den;
    agg_core(node, lane, offs, srcs, el, er, hf, acc, den);
    int q = lane & 15;
    float inv = 1.0f / fmaxf(den, 1e-30f);
    float o[8];
#pragma unroll
    for (int i = 0; i < 8; i++) o[i] = acc[i] * inv + bias[q * 8 + i];
#pragma unroll
    for (int i = 0; i < 8; i++) {
        o[i] += __shfl_xor(o[i], 4);
        o[i] += __shfl_xor(o[i], 8);
        o[i] = fmaxf(0.25f * o[i], 0.f);
    }
    int d0 = (q & 3) * 8;
    float l0 = 0.f, l1 = 0.f;
#pragma unroll
    for (int i = 0; i < 8; i++) {
        l0 += o[i] * Wout[(d0 + i) * 2];
        l1 += o[i] * Wout[(d0 + i) * 2 + 1];
    }
    l0 += __shfl_xor(l0, 1); l0 += __shfl_xor(l0, 2);
    l1 += __shfl_xor(l1, 1); l1 += __shfl_xor(l1, 2);
    if (lane == 0) {
        l0 += bout[0];
        l1 += bout[1];
        float mx = fmaxf(l0, l1);
        float e0 = __expf(l0 - mx), e1 = __expf(l1 - mx);
        float invs = 1.f / (e0 + e1);
        out[node] = make_float2(e0 * invs, e1 * invs);
    }
}

extern "C" void kernel_launch(void* const* d_in, const int* in_sizes, int n_in,
                              void* d_out, int out_size, void* d_ws, size_t ws_size,
                              hipStream_t stream) {
    const float* in_feat = (const float*)d_in[0];
    const float* W1   = (const float*)d_in[1];
    const float* al1  = (const float*)d_in[2];
    const float* ar1  = (const float*)d_in[3];
    const float* b1   = (const float*)d_in[4];
    const float* W2   = (const float*)d_in[5];
    const float* al2  = (const float*)d_in[6];
    const float* ar2  = (const float*)d_in[7];
    const float* b2   = (const float*)d_in[8];
    const float* Wout = (const float*)d_in[9];
    const float* bout = (const float*)d_in[10];
    const int*   src  = (const int*)d_in[11];
    const int*   dst  = (const int*)d_in[12];
    float* out = (float*)d_out;

    char* ws = (char*)d_ws;
    size_t off = 0;
    auto carve = [&](size_t bytes) {
        char* p = ws + off;
        off = (off + bytes + 255) & ~(size_t)255;
        return p;
    };
    u16*   hfA      = (u16*)carve((size_t)N_NODES * 128 * 2);
    u16*   h1       = (u16*)carve((size_t)N_NODES * 128 * 2);
    float* el       = (float*)carve((size_t)N_NODES * 4 * 4);
    float* er       = (float*)carve((size_t)N_NODES * 4 * 4);
    u16*   srcs     = (u16*)carve((size_t)N_EDGES * 2);
    u32*   bucketed = (u32*)carve((size_t)N_EDGES * 4);
    u32*   bcnt     = (u32*)carve((size_t)NHB * NBUCK * 4);
    u32*   wbase    = (u32*)carve((size_t)NHB * NBUCK * 4);
    int*   bstart   = (int*)carve((size_t)(NBUCK + 1) * 4);
    int*   offs     = (int*)carve((size_t)(N_NODES + 1) * 4);
    (void)ws_size; (void)in_sizes; (void)n_in; (void)out_size;

    const int GB = (N_NODES + 63) / 64;          // 782
    const int AB = (N_NODES + 3) / 4;            // 12500

    // bucketed CSR build
    bhist_k<<<NHB, 1024, 0, stream>>>(dst, bcnt);
    bscan_k<<<1, 256, 0, stream>>>(bcnt, wbase, bstart);
    bscatter_k<<<NHB, 1024, 0, stream>>>(src, dst, wbase, bstart, bucketed);
    bcsr_k<<<NBUCK, 256, 0, stream>>>(bucketed, bstart, offs, srcs);

    // layer 1
    gemm_attn<0><<<GB, 256, 0, stream>>>(in_feat, W1, al1, ar1, hfA, el, er, N_NODES);
    agg1_k<<<AB, 256, 0, stream>>>(offs, srcs, el, er, hfA, b1, h1);

    // layer 2
    gemm_attn<1><<<GB, 256, 0, stream>>>(h1, W2, al2, ar2, hfA, el, er, N_NODES);
    agg2_k<<<AB, 256, 0, stream>>>(offs, srcs, el, er, hfA, b2, Wout, bout, (float2*)out);
}

// Round 6
// 226.307 us; speedup vs baseline: 2.5035x; 1.1771x over previous
//
#include <hip/hip_runtime.h>
#include <cmath>

#define N_NODES 50000
#define N_EDGES 800000
#define NBUCK 196          // buckets of 256 nodes: bucket = dst >> 8
#define NHB 196            // histogram blocks, 4096 edges each
#define EPB 4096
// IN_DIM = HEADS*HID = 128, HEADS=4, HID=32

typedef unsigned short u16;
typedef unsigned int u32;
typedef __attribute__((ext_vector_type(8))) short bf16x8;
typedef __attribute__((ext_vector_type(4))) float f32x4;

static __device__ __forceinline__ float lrelu(float x) { return x > 0.f ? x : 0.2f * x; }
static __device__ __forceinline__ float bf2f(u16 u) { return __uint_as_float(((u32)u) << 16); }
static __device__ __forceinline__ float bflo(u32 u) { return __uint_as_float(u << 16); }
static __device__ __forceinline__ float bfhi(u32 u) { return __uint_as_float(u & 0xFFFF0000u); }
static __device__ __forceinline__ u16 f2bf(float f) {
    u32 b = __float_as_uint(f);
    return (u16)((b + 0x7FFFu + ((b >> 16) & 1u)) >> 16);  // RNE
}
static __device__ __forceinline__ u32 pack2(float a, float b) {
    return (u32)f2bf(a) | ((u32)f2bf(b) << 16);
}

// ---------------- bucketed CSR build ----------------
__global__ __launch_bounds__(1024) void bhist_k(const int* __restrict__ dst, u32* __restrict__ bcnt) {
    __shared__ u32 hist[NBUCK];
    int tid = threadIdx.x;
    for (int i = tid; i < NBUCK; i += 1024) hist[i] = 0;
    __syncthreads();
    int base = blockIdx.x * EPB;
#pragma unroll
    for (int k = 0; k < 4; ++k) {
        int e = base + k * 1024 + tid;
        if (e < N_EDGES) atomicAdd(&hist[dst[e] >> 8], 1u);
    }
    __syncthreads();
    for (int i = tid; i < NBUCK; i += 1024) bcnt[(size_t)blockIdx.x * NBUCK + i] = hist[i];
}

__global__ __launch_bounds__(256) void bscan_k(const u32* __restrict__ bcnt, u32* __restrict__ wbase,
                                               int* __restrict__ bstart) {
    __shared__ int s[256];
    int t = threadIdx.x;
    u32 run = 0;
    if (t < NBUCK) {
        for (int blk = 0; blk < NHB; ++blk) {
            u32 v = bcnt[(size_t)blk * NBUCK + t];
            wbase[(size_t)blk * NBUCK + t] = run;
            run += v;
        }
    }
    s[t] = (t < NBUCK) ? (int)run : 0;
    __syncthreads();
    for (int o = 1; o < 256; o <<= 1) {
        int v = (t >= o) ? s[t - o] : 0;
        __syncthreads();
        s[t] += v;
        __syncthreads();
    }
    if (t < NBUCK) bstart[t] = (t == 0) ? 0 : s[t - 1];
    if (t == NBUCK - 1) bstart[NBUCK] = s[t];
}

__global__ __launch_bounds__(1024) void bscatter_k(const int* __restrict__ src, const int* __restrict__ dst,
                                                   const u32* __restrict__ wbase, const int* __restrict__ bstart,
                                                   u32* __restrict__ bucketed) {
    __shared__ u32 pos[NBUCK];
    int tid = threadIdx.x;
    for (int i = tid; i < NBUCK; i += 1024)
        pos[i] = (u32)bstart[i] + wbase[(size_t)blockIdx.x * NBUCK + i];
    __syncthreads();
    int base = blockIdx.x * EPB;
#pragma unroll
    for (int k = 0; k < 4; ++k) {
        int e = base + k * 1024 + tid;
        if (e < N_EDGES) {
            int d = dst[e];
            int b = d >> 8;
            u32 p = atomicAdd(&pos[b], 1u);
            bucketed[p] = (u32)src[e] | ((u32)(d & 255) << 16);
        }
    }
}

__global__ __launch_bounds__(256) void bcsr_k(const u32* __restrict__ bucketed, const int* __restrict__ bstart,
                                              int* __restrict__ offs, u16* __restrict__ srcs) {
    __shared__ u32 cnt[256];
    __shared__ int s[256];
    __shared__ u32 fp[256];
    int b = blockIdx.x;
    int tid = threadIdx.x;
    int ebeg = bstart[b], eend = bstart[b + 1];
    int ne = eend - ebeg;
    cnt[tid] = 0;
    __syncthreads();
    for (int i = tid; i < ne; i += 256)
        atomicAdd(&cnt[bucketed[ebeg + i] >> 16], 1u);
    __syncthreads();
    s[tid] = (int)cnt[tid];
    __syncthreads();
    for (int o = 1; o < 256; o <<= 1) {
        int v = (tid >= o) ? s[tid - o] : 0;
        __syncthreads();
        s[tid] += v;
        __syncthreads();
    }
    int excl = s[tid] - (int)cnt[tid];
    int node = b * 256 + tid;
    if (node < N_NODES) offs[node] = ebeg + excl;
    if (b == NBUCK - 1 && tid == 0) offs[N_NODES] = N_EDGES;
    fp[tid] = (u32)excl;
    __syncthreads();
    for (int i = tid; i < ne; i += 256) {
        u32 u = bucketed[ebeg + i];
        u32 p = atomicAdd(&fp[u >> 16], 1u);
        srcs[ebeg + p] = (u16)(u & 0xFFFFu);
    }
}

// ---------------- W pre-pack: fp32 W[128][128] -> bf16 B-fragment order ----------------
// Wp[((nt*4+ks)*64+lane)*8+j] = bf16(W[ks*32 + (lane>>4)*8 + j][nt*16 + (lane&15)])
__global__ __launch_bounds__(256) void packW_k(const float* __restrict__ W, u16* __restrict__ Wp) {
    int i = blockIdx.x * 256 + threadIdx.x;
    if (i >= 16384) return;
    int j = i & 7, lane = (i >> 3) & 63, ks = (i >> 9) & 3, nt = i >> 11;
    int k = ks * 32 + (lane >> 4) * 8 + j;
    int ncol = nt * 16 + (lane & 15);
    Wp[i] = f2bf(W[k * 128 + ncol]);
}

// ---------------- MFMA GEMM (X[N,128] @ W[128,128]) fused with el/er head dots ----------------
// block = 256 thr = 4 waves; block tile 64 rows x 128 cols; wave w owns cols [w*32, w*32+32) = head w.
template <int BF16IN>
__global__ __launch_bounds__(256) void gemm_mfma(
    const void* __restrict__ Xv, const u16* __restrict__ Wp,
    const float* __restrict__ al, const float* __restrict__ ar,
    u16* __restrict__ hf, float* __restrict__ el, float* __restrict__ er, int n)
{
    __shared__ u16 xs[64][136];   // +8 pad: row stride 272B -> 2-way LDS bank aliasing (free)
    int row0 = blockIdx.x * 64;
    int tid = threadIdx.x;
    if (BF16IN) {
        const uint4* Xb = (const uint4*)Xv;   // 8 bf16 per uint4, 16 per row
        for (int i = tid; i < 1024; i += 256) {
            int r = i >> 4, c = i & 15;
            uint4 v = make_uint4(0u, 0u, 0u, 0u);
            if (row0 + r < n) v = Xb[(size_t)(row0 + r) * 16 + c];
            ((uint4*)&xs[r][0])[c] = v;
        }
    } else {
        const float4* X4 = (const float4*)Xv;  // 32 float4 per row
        for (int i = tid; i < 2048; i += 256) {
            int r = i >> 5, c = i & 31;
            float4 v = make_float4(0.f, 0.f, 0.f, 0.f);
            if (row0 + r < n) v = X4[(size_t)(row0 + r) * 32 + c];
            ((uint2*)&xs[r][0])[c] = make_uint2(pack2(v.x, v.y), pack2(v.z, v.w));
        }
    }
    __syncthreads();

    int wave = tid >> 6, lane = tid & 63;
    int quad = lane >> 4, l15 = lane & 15;

    // B fragments: 2 col-tiles x 4 k-steps, one 16B load each
    bf16x8 bfrag[2][4];
#pragma unroll
    for (int ct = 0; ct < 2; ++ct) {
        int nt = wave * 2 + ct;
#pragma unroll
        for (int ks = 0; ks < 4; ++ks)
            bfrag[ct][ks] = *(const bf16x8*)(Wp + ((((nt * 4 + ks) * 64) + lane) << 3));
    }

    f32x4 acc[4][2];
#pragma unroll
    for (int rt = 0; rt < 4; ++rt)
#pragma unroll
        for (int ct = 0; ct < 2; ++ct)
            acc[rt][ct] = (f32x4){0.f, 0.f, 0.f, 0.f};

#pragma unroll
    for (int ks = 0; ks < 4; ++ks) {
#pragma unroll
        for (int rt = 0; rt < 4; ++rt) {
            bf16x8 a = *(const bf16x8*)&xs[rt * 16 + l15][ks * 32 + quad * 8];
            acc[rt][0] = __builtin_amdgcn_mfma_f32_16x16x32_bf16(a, bfrag[0][ks], acc[rt][0], 0, 0, 0);
            acc[rt][1] = __builtin_amdgcn_mfma_f32_16x16x32_bf16(a, bfrag[1][ks], acc[rt][1], 0, 0, 0);
        }
    }

    // epilogue: hf (bf16) + el/er (head = wave), C/D layout: col=l15, row=quad*4+reg
    float alv0 = al[wave * 32 + l15], alv1 = al[wave * 32 + 16 + l15];
    float arv0 = ar[wave * 32 + l15], arv1 = ar[wave * 32 + 16 + l15];
#pragma unroll
    for (int rt = 0; rt < 4; ++rt) {
#pragma unroll
        for (int r = 0; r < 4; ++r) {
            int row = row0 + rt * 16 + quad * 4 + r;
            float c0 = acc[rt][0][r], c1 = acc[rt][1][r];
            if (row < n) {
                hf[(size_t)row * 128 + wave * 32 + l15] = f2bf(c0);
                hf[(size_t)row * 128 + wave * 32 + 16 + l15] = f2bf(c1);
            }
            float pel = c0 * alv0 + c1 * alv1;
            float per = c0 * arv0 + c1 * arv1;
            pel += __shfl_xor(pel, 1); pel += __shfl_xor(pel, 2);
            pel += __shfl_xor(pel, 4); pel += __shfl_xor(pel, 8);
            per += __shfl_xor(per, 1); per += __shfl_xor(per, 2);
            per += __shfl_xor(per, 4); per += __shfl_xor(per, 8);
            if (l15 == 0 && row < n) {
                el[row * 4 + wave] = pel;
                er[row * 4 + wave] = per;
            }
        }
    }
}

// ---------------- agg core: quarter-wave per edge, lane owns 8 features (uint4 of bf16) ---------
static __device__ __forceinline__ void agg_core(
    int node, int lane, const int* __restrict__ offs, const u16* __restrict__ srcs,
    const float* __restrict__ el, const float* __restrict__ er, const u16* __restrict__ hf,
    float acc[8], float& den)
{
    int qw = lane >> 4;
    int q = lane & 15;
    int h = q >> 2;
    float erh = er[node * 4 + h];
    int beg = offs[node], end = offs[node + 1];
    den = 0.f;
#pragma unroll
    for (int i = 0; i < 8; i++) acc[i] = 0.f;
    int base = beg;
    for (; base + 8 <= end; base += 8) {
        int s0 = srcs[base + qw];
        int s1 = srcs[base + 4 + qw];
        float w0 = __expf(lrelu(el[s0 * 4 + h] + erh));
        float w1 = __expf(lrelu(el[s1 * 4 + h] + erh));
        uint4 u0 = *(const uint4*)(hf + (size_t)s0 * 128 + q * 8);
        uint4 u1 = *(const uint4*)(hf + (size_t)s1 * 128 + q * 8);
        den += w0 + w1;
        acc[0] += w0 * bflo(u0.x) + w1 * bflo(u1.x);
        acc[1] += w0 * bfhi(u0.x) + w1 * bfhi(u1.x);
        acc[2] += w0 * bflo(u0.y) + w1 * bflo(u1.y);
        acc[3] += w0 * bfhi(u0.y) + w1 * bfhi(u1.y);
        acc[4] += w0 * bflo(u0.z) + w1 * bflo(u1.z);
        acc[5] += w0 * bfhi(u0.z) + w1 * bfhi(u1.z);
        acc[6] += w0 * bflo(u0.w) + w1 * bflo(u1.w);
        acc[7] += w0 * bfhi(u0.w) + w1 * bfhi(u1.w);
    }
    for (; base < end; base += 4) {
        int e = base + qw;
        bool valid = e < end;
        int ec = valid ? e : end - 1;
        int s = srcs[ec];
        float w = valid ? __expf(lrelu(el[s * 4 + h] + erh)) : 0.f;
        uint4 u = *(const uint4*)(hf + (size_t)s * 128 + q * 8);
        den += w;
        acc[0] += w * bflo(u.x);
        acc[1] += w * bfhi(u.x);
        acc[2] += w * bflo(u.y);
        acc[3] += w * bfhi(u.y);
        acc[4] += w * bflo(u.z);
        acc[5] += w * bfhi(u.z);
        acc[6] += w * bflo(u.w);
        acc[7] += w * bfhi(u.w);
    }
#pragma unroll
    for (int i = 0; i < 8; i++) {
        acc[i] += __shfl_xor(acc[i], 16);
        acc[i] += __shfl_xor(acc[i], 32);
    }
    den += __shfl_xor(den, 16);
    den += __shfl_xor(den, 32);
}

// ---------------- layer-1 aggregation (relu, bf16 out) ----------------
__global__ __launch_bounds__(256) void agg1_k(const int* __restrict__ offs, const u16* __restrict__ srcs,
                                              const float* __restrict__ el, const float* __restrict__ er,
                                              const u16* __restrict__ hf, const float* __restrict__ bias,
                                              u16* __restrict__ h1) {
    int node = blockIdx.x * 4 + (threadIdx.x >> 6);
    int lane = threadIdx.x & 63;
    if (node >= N_NODES) return;
    float acc[8], den;
    agg_core(node, lane, offs, srcs, el, er, hf, acc, den);
    int qw = lane >> 4, q = lane & 15;
    if (qw == 0) {
        float inv = 1.0f / fmaxf(den, 1e-30f);
        float o[8];
#pragma unroll
        for (int i = 0; i < 8; i++)
            o[i] = fmaxf(acc[i] * inv + bias[q * 8 + i], 0.f);
        uint4 pk;
        pk.x = pack2(o[0], o[1]);
        pk.y = pack2(o[2], o[3]);
        pk.z = pack2(o[4], o[5]);
        pk.w = pack2(o[6], o[7]);
        *(uint4*)(h1 + (size_t)node * 128 + q * 8) = pk;
    }
}

// ---------------- layer-2 aggregation fused with head-mean/relu/proj/softmax ----------------
__global__ __launch_bounds__(256) void agg2_k(const int* __restrict__ offs, const u16* __restrict__ srcs,
                                              const float* __restrict__ el, const float* __restrict__ er,
                                              const u16* __restrict__ hf, const float* __restrict__ bias,
                                              const float* __restrict__ Wout, const float* __restrict__ bout,
                                              float2* __restrict__ out) {
    int node = blockIdx.x * 4 + (threadIdx.x >> 6);
    int lane = threadIdx.x & 63;
    if (node >= N_NODES) return;
    float acc[8], den;
    agg_core(node, lane, offs, srcs, el, er, hf, acc, den);
    int q = lane & 15;
    float inv = 1.0f / fmaxf(den, 1e-30f);
    float o[8];
#pragma unroll
    for (int i = 0; i < 8; i++) o[i] = acc[i] * inv + bias[q * 8 + i];
#pragma unroll
    for (int i = 0; i < 8; i++) {
        o[i] += __shfl_xor(o[i], 4);
        o[i] += __shfl_xor(o[i], 8);
        o[i] = fmaxf(0.25f * o[i], 0.f);
    }
    int d0 = (q & 3) * 8;
    float l0 = 0.f, l1 = 0.f;
#pragma unroll
    for (int i = 0; i < 8; i++) {
        l0 += o[i] * Wout[(d0 + i) * 2];
        l1 += o[i] * Wout[(d0 + i) * 2 + 1];
    }
    l0 += __shfl_xor(l0, 1); l0 += __shfl_xor(l0, 2);
    l1 += __shfl_xor(l1, 1); l1 += __shfl_xor(l1, 2);
    if (lane == 0) {
        l0 += bout[0];
        l1 += bout[1];
        float mx = fmaxf(l0, l1);
        float e0 = __expf(l0 - mx), e1 = __expf(l1 - mx);
        float invs = 1.f / (e0 + e1);
        out[node] = make_float2(e0 * invs, e1 * invs);
    }
}

extern "C" void kernel_launch(void* const* d_in, const int* in_sizes, int n_in,
                              void* d_out, int out_size, void* d_ws, size_t ws_size,
                              hipStream_t stream) {
    const float* in_feat = (const float*)d_in[0];
    const float* W1   = (const float*)d_in[1];
    const float* al1  = (const float*)d_in[2];
    const float* ar1  = (const float*)d_in[3];
    const float* b1   = (const float*)d_in[4];
    const float* W2   = (const float*)d_in[5];
    const float* al2  = (const float*)d_in[6];
    const float* ar2  = (const float*)d_in[7];
    const float* b2   = (const float*)d_in[8];
    const float* Wout = (const float*)d_in[9];
    const float* bout = (const float*)d_in[10];
    const int*   src  = (const int*)d_in[11];
    const int*   dst  = (const int*)d_in[12];
    float* out = (float*)d_out;

    char* ws = (char*)d_ws;
    size_t off = 0;
    auto carve = [&](size_t bytes) {
        char* p = ws + off;
        off = (off + bytes + 255) & ~(size_t)255;
        return p;
    };
    u16*   hfA      = (u16*)carve((size_t)N_NODES * 128 * 2);
    u16*   h1       = (u16*)carve((size_t)N_NODES * 128 * 2);
    float* el       = (float*)carve((size_t)N_NODES * 4 * 4);
    float* er       = (float*)carve((size_t)N_NODES * 4 * 4);
    u16*   srcs     = (u16*)carve((size_t)N_EDGES * 2);
    u32*   bucketed = (u32*)carve((size_t)N_EDGES * 4);
    u32*   bcnt     = (u32*)carve((size_t)NHB * NBUCK * 4);
    u32*   wbase    = (u32*)carve((size_t)NHB * NBUCK * 4);
    int*   bstart   = (int*)carve((size_t)(NBUCK + 1) * 4);
    int*   offs     = (int*)carve((size_t)(N_NODES + 1) * 4);
    u16*   Wp1      = (u16*)carve((size_t)16384 * 2);
    u16*   Wp2      = (u16*)carve((size_t)16384 * 2);
    (void)ws_size; (void)in_sizes; (void)n_in; (void)out_size;

    const int GB = (N_NODES + 63) / 64;          // 782
    const int AB = (N_NODES + 3) / 4;            // 12500

    // bucketed CSR build + weight pre-pack
    bhist_k<<<NHB, 1024, 0, stream>>>(dst, bcnt);
    packW_k<<<64, 256, 0, stream>>>(W1, Wp1);
    packW_k<<<64, 256, 0, stream>>>(W2, Wp2);
    bscan_k<<<1, 256, 0, stream>>>(bcnt, wbase, bstart);
    bscatter_k<<<NHB, 1024, 0, stream>>>(src, dst, wbase, bstart, bucketed);
    bcsr_k<<<NBUCK, 256, 0, stream>>>(bucketed, bstart, offs, srcs);

    // layer 1
    gemm_mfma<0><<<GB, 256, 0, stream>>>(in_feat, Wp1, al1, ar1, hfA, el, er, N_NODES);
    agg1_k<<<AB, 256, 0, stream>>>(offs, srcs, el, er, hfA, b1, h1);

    // layer 2
    gemm_mfma<1><<<GB, 256, 0, stream>>>(h1, Wp2, al2, ar2, hfA, el, er, N_NODES);
    agg2_k<<<AB, 256, 0, stream>>>(offs, srcs, el, er, hfA, b2, Wout, bout, (float2*)out);
}